// Round 6
// baseline (413.693 us; speedup 1.0000x reference)
//
#include <hip/hip_runtime.h>
#include <cstdint>

#define N_TOK 16384
#define HID   4096
#define NEXP  64
#define AUXW  0.01f

typedef __attribute__((ext_vector_type(4))) _Float16 f16x4;
typedef __attribute__((ext_vector_type(8))) _Float16 f16x8;
typedef __attribute__((ext_vector_type(4))) float f32x4;

typedef const __attribute__((address_space(1))) void gvoid_t;
typedef __attribute__((address_space(3))) void lvoid_t;

__device__ __forceinline__ void async_cp16(const void* g, void* l) {
  __builtin_amdgcn_global_load_lds((gvoid_t*)g, (lvoid_t*)l, 16, 0, 0);
}

// 3-way f16 split: x = H+M+L, dropped residual ~2^-33|x| -> fp32-grade logits.
__device__ __forceinline__ void split3_f4(f32x4 p, f16x4& H, f16x4& M, f16x4& L) {
#pragma unroll
  for (int j = 0; j < 4; ++j) {
    _Float16 h = (_Float16)p[j];
    float r1 = p[j] - (float)h;
    _Float16 m = (_Float16)r1;
    float r2 = r1 - (float)m;
    H[j] = h; M[j] = m; L[j] = (_Float16)r2;
  }
}

// W (64x4096 f32) -> step-contiguous swizzled f16 H/M/L image.
// Step s (0..63) holds 24KB: [kg(2)][level(3)][row 64][field(4)]x16B,
// field p stores logical granule p^(row&3) (involution; reader XORs same).
__global__ void presplit_w(const float* __restrict__ Wg, char* __restrict__ img) {
  int id = blockIdx.x * 256 + threadIdx.x;   // 0..32767
  int r  = id >> 9;                          // expert row 0..63
  int gc = (id >> 2) & 127;                  // global k-chunk (32 f32)
  int gq = id & 3;                           // logical granule (8 f16)
  const float* src = Wg + (size_t)r * HID + gc * 32 + gq * 8;
  f32x4 p0 = *(const f32x4*)src;
  f32x4 p1 = *(const f32x4*)(src + 4);
  f16x4 h0, m0, l0, h1, m1, l1;
  split3_f4(p0, h0, m0, l0);
  split3_f4(p1, h1, m1, l1);
  int step = gc & 63, kg = gc >> 6;
  char* base = img + (size_t)step * 24576 + kg * 12288 + r * 64 + ((gq ^ (r & 3)) << 4);
  *(f16x4*)(base)            = h0;  *(f16x4*)(base + 8)        = h1;
  *(f16x4*)(base + 4096)     = m0;  *(f16x4*)(base + 4096 + 8) = m1;
  *(f16x4*)(base + 8192)     = l0;  *(f16x4*)(base + 8192 + 8) = l1;
}

// 256 blocks x 512 thr (8 waves = tg(4) x kg(2)); block = 64 tokens x 64 experts.
// A: direct global->reg split (depth-3 nt prefetch). W: LDS dbuf 2x24KB via
// global_load_lds. One raw s_barrier + counted vmcnt per chunk; no drains.
__global__ __launch_bounds__(512) void router_main(
    const float* __restrict__ hs, const char* __restrict__ wimg,
    float* __restrict__ out, float* __restrict__ Sacc) {
  __shared__ __align__(16) char smem[49152];
  const int tid = threadIdx.x;
  const int lane = tid & 63, wv = tid >> 6;
  const int tg = wv & 3, kg = wv >> 2;
  const int l15 = lane & 15, l4 = lane >> 4;
  const int tb = blockIdx.x * 64;

  // A: row = token, lane k-slot = l4*8; chunk c covers k = kg*2048 + c*32
  const float* ap = hs + (size_t)(tb + tg * 16 + l15) * HID + kg * 2048 + l4 * 8;
  const char* wsp = wimg + (size_t)tid * 16;

  int boff[4];
#pragma unroll
  for (int eg = 0; eg < 4; ++eg) {
    int r = eg * 16 + l15;
    boff[eg] = kg * 12288 + r * 64 + ((l4 ^ (r & 3)) << 4);
  }

  f32x4 acc[4];
#pragma unroll
  for (int eg = 0; eg < 4; ++eg) acc[eg] = (f32x4){0.f, 0.f, 0.f, 0.f};

  auto stage = [&](int c) {
    char* dst = smem + (c & 1) * 24576;
#pragma unroll
    for (int it = 0; it < 3; ++it)
      async_cp16(wsp + (size_t)c * 24576 + it * 8192, dst + tid * 16 + it * 8192);
  };
  auto loadA = [&](int c, f32x4& x, f32x4& y) {
    const f32x4* p = (const f32x4*)(ap + c * 32);
    x = __builtin_nontemporal_load(p);
    y = __builtin_nontemporal_load(p + 1);
  };
  auto mk8 = [](f16x4 a, f16x4 b) {
    f16x8 r;
#pragma unroll
    for (int j = 0; j < 4; ++j) { r[j] = a[j]; r[j + 4] = b[j]; }
    return r;
  };

  f16x8 aH, aM, aL;
  auto split_in = [&](f32x4 x, f32x4 y) {
    f16x4 h0, m0, l0, h1, m1, l1;
    split3_f4(x, h0, m0, l0);
    split3_f4(y, h1, m1, l1);
    aH = mk8(h0, h1); aM = mk8(m0, m1); aL = mk8(l0, l1);
  };
  auto compute = [&](int c) {
    const char* buf = smem + (c & 1) * 24576;
#pragma unroll
    for (int eg = 0; eg < 4; ++eg) {
      f16x8 bH = *(const f16x8*)(buf + boff[eg]);
      f16x8 bM = *(const f16x8*)(buf + 4096 + boff[eg]);
      f16x8 bL = *(const f16x8*)(buf + 8192 + boff[eg]);
      f32x4 a = acc[eg];
      a = __builtin_amdgcn_mfma_f32_16x16x32_f16(aH, bH, a, 0, 0, 0);
      a = __builtin_amdgcn_mfma_f32_16x16x32_f16(aH, bM, a, 0, 0, 0);
      a = __builtin_amdgcn_mfma_f32_16x16x32_f16(aM, bH, a, 0, 0, 0);
      a = __builtin_amdgcn_mfma_f32_16x16x32_f16(aH, bL, a, 0, 0, 0);
      a = __builtin_amdgcn_mfma_f32_16x16x32_f16(aL, bH, a, 0, 0, 0);
      a = __builtin_amdgcn_mfma_f32_16x16x32_f16(aM, bM, a, 0, 0, 0);
      acc[eg] = a;
    }
  };

  f32x4 a1x, a1y, a2x, a2y, a3x, a3y;
  // prologue: establish invariant entry(0): a1=A(0),a2=A(1),a3=A(2);
  // stage(0),stage(1) issued; own stage(0) done before barrier.
  stage(0); loadA(0, a1x, a1y); loadA(1, a2x, a2y);
  stage(1); loadA(2, a3x, a3y);
  asm volatile("s_waitcnt vmcnt(9)\n\ts_barrier" ::: "memory");

  // steady: c = 0..60 full body
  for (int c = 0; c < 61; ++c) {
    split_in(a1x, a1y);                // compiler waits A(c) (oldest) - cheap
    compute(c);
    asm volatile("s_waitcnt vmcnt(2)\n\ts_barrier" ::: "memory");  // stage(c+1) done; A(c+2) flies
    stage(c + 2);                      // overwrite buffer just freed by barrier
    a1x = a2x; a1y = a2y; a2x = a3x; a2y = a3y;
    loadA(c + 3, a3x, a3y);
  }
  // c = 61: no more A loads
  split_in(a1x, a1y);
  compute(61);
  asm volatile("s_waitcnt vmcnt(2)\n\ts_barrier" ::: "memory");
  stage(63);
  a1x = a2x; a1y = a2y; a2x = a3x; a2y = a3y;
  // c = 62: no stage; must fully drain so stage(63) visible
  split_in(a1x, a1y);
  compute(62);
  asm volatile("s_waitcnt vmcnt(0)\n\ts_barrier" ::: "memory");
  a1x = a2x; a1y = a2y;
  // c = 63 final
  split_in(a1x, a1y);
  compute(63);
  __syncthreads();

  // ---- epilogue: kg-reduce, top-2, outputs ----
  float* red   = (float*)smem;               // [64][64] 16KB
  float* lg    = (float*)(smem + 16384);     // [64][73]
  float* S_lds = (float*)(smem + 35072);     // 64
  int*   e1a   = (int*)(smem + 35328);       // 64
  int*   e2a   = (int*)(smem + 35584);       // 64

  if (kg == 1) {
#pragma unroll
    for (int eg = 0; eg < 4; ++eg)
#pragma unroll
      for (int r = 0; r < 4; ++r)
        red[(tg * 16 + l4 * 4 + r) * 64 + eg * 16 + l15] = acc[eg][r];
  }
  if (tid < 64) S_lds[tid] = 0.f;
  __syncthreads();
  if (kg == 0) {
#pragma unroll
    for (int eg = 0; eg < 4; ++eg)
#pragma unroll
      for (int r = 0; r < 4; ++r) {
        int t = tg * 16 + l4 * 4 + r, e = eg * 16 + l15;
        lg[t * 73 + e] = acc[eg][r] + red[t * 64 + e];
      }
  }
  __syncthreads();

  if (tid < 64) {
    const float* row = lg + tid * 73;
    float m1 = -1e30f, m2 = -1e30f;
    int i1 = 0, i2 = 0;
    for (int e = 0; e < NEXP; ++e) {
      float v = row[e];
      if (v > m1)      { m2 = m1; i2 = i1; m1 = v; i1 = e; }
      else if (v > m2) { m2 = v;  i2 = e; }
    }
    float qq = expf(m2 - m1);          // renorm top-2 = 2-way softmax
    float w1 = 1.f / (1.f + qq);
    float w2 = qq * w1;
    float* comb = out + (size_t)N_TOK * 2 * NEXP;
    comb[(size_t)(tb + tid) * 2]     = w1;
    comb[(size_t)(tb + tid) * 2 + 1] = w2;
    e1a[tid] = i1; e2a[tid] = i2;
    atomicAdd(&S_lds[i1], w1);
    atomicAdd(&S_lds[i2], w2);
  }
  __syncthreads();
  if (tid < 64) {
    float s = S_lds[tid];
    if (s != 0.f) atomicAdd(&Sacc[tid], s);
  }

  // one-hot dispatch mask: 64 tok x 2 slots x 16 float4-granules = 2048
#pragma unroll
  for (int it = 0; it < 4; ++it) {
    int f = it * 512 + tid;
    int tok = f >> 5, rem = f & 31, sl = rem >> 4, g = rem & 15;
    int sel = sl ? e2a[tok] : e1a[tok];
    int base = g << 2;
    float4 v;
    v.x = (sel == base)     ? 1.f : 0.f;
    v.y = (sel == base + 1) ? 1.f : 0.f;
    v.z = (sel == base + 2) ? 1.f : 0.f;
    v.w = (sel == base + 3) ? 1.f : 0.f;
    *(float4*)(out + ((size_t)(tb + tok) * 2 + sl) * 64 + base) = v;
  }
}

__global__ void aux_k(const float* __restrict__ S, float* __restrict__ out) {
  float v = S[threadIdx.x];
  float s = v * v;
#pragma unroll
  for (int off = 32; off > 0; off >>= 1) s += __shfl_down(s, off);
  if (threadIdx.x == 0)
    out[(size_t)N_TOK * 2 * NEXP + (size_t)N_TOK * 2] = s * (AUXW / (float)N_TOK);
}

extern "C" void kernel_launch(void* const* d_in, const int* in_sizes, int n_in,
                              void* d_out, int out_size, void* d_ws, size_t ws_size,
                              hipStream_t stream) {
  const float* hs = (const float*)d_in[0];
  const float* Wg = (const float*)d_in[1];
  float* out = (float*)d_out;
  float* S = (float*)d_ws;                 // 64 floats
  char* img = (char*)d_ws + 256;           // 1.5 MB W image
  hipMemsetAsync(d_ws, 0, 256, stream);
  hipLaunchKernelGGL(presplit_w, dim3(128), dim3(256), 0, stream, Wg, img);
  hipLaunchKernelGGL(router_main, dim3(N_TOK / 64), dim3(512), 0, stream,
                     hs, img, out, S);
  hipLaunchKernelGGL(aux_k, dim3(1), dim3(64), 0, stream, S, out);
}